// Round 1
// baseline (1018.715 us; speedup 1.0000x reference)
//
#include <hip/hip_runtime.h>

// Problem constants (from reference)
#define EMBED_DIM 200
#define NUM_WALKS 25
#define NUM_LAYERS 3
#define BATCH 8192

// One wave (64 lanes) per batch element. Lanes 0..49 each own a float4 slice
// of the 200-dim embedding row (50*4 = 200). Walk indices (100 int32 per
// element) are preloaded as int2 across lanes and broadcast via __shfl.
__global__ __launch_bounds__(256) void gnp_score_kernel(
    const float* __restrict__ emb,      // [1e6, 200]
    const float* __restrict__ lw,       // [4] layer weights (pre-softmax)
    const int*   __restrict__ uidx,     // [B]
    const int*   __restrict__ iidx,     // [B]
    const int*   __restrict__ uwalks,   // [B, 25, 4]
    const int*   __restrict__ iwalks,   // [B, 25, 4]
    float*       __restrict__ out)      // [B]
{
    const int lane = threadIdx.x & 63;
    const int wave = threadIdx.x >> 6;
    const int b = blockIdx.x * 4 + wave;

    // softmax over 4 layer weights (uniform values; computed per-lane, cheap)
    const float l0 = lw[0], l1 = lw[1], l2 = lw[2], l3 = lw[3];
    const float mx = fmaxf(fmaxf(l0, l1), fmaxf(l2, l3));
    const float e0 = expf(l0 - mx), e1 = expf(l1 - mx);
    const float e2 = expf(l2 - mx), e3 = expf(l3 - mx);
    const float inv = 1.0f / (e0 + e1 + e2 + e3);
    const float w0 = e0 * inv;                         // base-row weight
    const float c1 = e1 * inv * (1.0f / NUM_WALKS);    // layer-mean weights / 25
    const float c2 = e2 * inv * (1.0f / NUM_WALKS);
    const float c3 = e3 * inv * (1.0f / NUM_WALKS);

    float partial = 0.0f;

    if (lane < 50) {
        // Preload this element's 100 walk indices: lane L holds ints {2L, 2L+1}
        const int2 uw = ((const int2*)(uwalks + b * 100))[lane];
        const int2 iw = ((const int2*)(iwalks + b * 100))[lane];

        const unsigned doff = (unsigned)lane * 4u;  // float offset within row

        // Base rows (weight w0)
        float4 ua, ia;
        {
            const unsigned uo = (unsigned)uidx[b] * 200u + doff;
            const unsigned io = (unsigned)iidx[b] * 200u + doff;
            const float4 uv = *(const float4*)(emb + uo);
            const float4 iv = *(const float4*)(emb + io);
            ua.x = w0 * uv.x; ua.y = w0 * uv.y; ua.z = w0 * uv.z; ua.w = w0 * uv.w;
            ia.x = w0 * iv.x; ia.y = w0 * iv.y; ia.z = w0 * iv.z; ia.w = w0 * iv.w;
        }

        // Walk rows: layers k=1..3 (walks[:, :, 1:]), weight c_k = w_k/25
        #pragma unroll
        for (int k = 1; k <= NUM_LAYERS; ++k) {
            const float c = (k == 1) ? c1 : (k == 2) ? c2 : c3;
            #pragma unroll 5
            for (int w = 0; w < NUM_WALKS; ++w) {
                const int f = w * 4 + k;                       // flat index in [0,100)
                const int su = __shfl((f & 1) ? uw.y : uw.x, f >> 1, 64);
                const int si = __shfl((f & 1) ? iw.y : iw.x, f >> 1, 64);
                const float4 uv = *(const float4*)(emb + (unsigned)su * 200u + doff);
                const float4 iv = *(const float4*)(emb + (unsigned)si * 200u + doff);
                ua.x = fmaf(c, uv.x, ua.x); ua.y = fmaf(c, uv.y, ua.y);
                ua.z = fmaf(c, uv.z, ua.z); ua.w = fmaf(c, uv.w, ua.w);
                ia.x = fmaf(c, iv.x, ia.x); ia.y = fmaf(c, iv.y, ia.y);
                ia.z = fmaf(c, iv.z, ia.z); ia.w = fmaf(c, iv.w, ia.w);
            }
        }

        partial = ua.x * ia.x + ua.y * ia.y + ua.z * ia.z + ua.w * ia.w;
    }

    // Wave-wide sum (lanes 50..63 contribute 0); all 64 lanes execute.
    #pragma unroll
    for (int off = 32; off > 0; off >>= 1)
        partial += __shfl_xor(partial, off, 64);

    if (lane == 0) out[b] = partial;
}

extern "C" void kernel_launch(void* const* d_in, const int* in_sizes, int n_in,
                              void* d_out, int out_size, void* d_ws, size_t ws_size,
                              hipStream_t stream) {
    const float* emb    = (const float*)d_in[0];
    const float* lw     = (const float*)d_in[1];
    const int*   uidx   = (const int*)d_in[2];
    const int*   iidx   = (const int*)d_in[3];
    const int*   uwalks = (const int*)d_in[4];
    const int*   iwalks = (const int*)d_in[5];
    float*       out    = (float*)d_out;

    // 4 waves (elements) per 256-thread block
    const int blocks = BATCH / 4;  // 2048
    gnp_score_kernel<<<blocks, 256, 0, stream>>>(emb, lw, uidx, iidx,
                                                 uwalks, iwalks, out);
}

// Round 2
// 1013.127 us; speedup vs baseline: 1.0055x; 1.0055x over previous
//
#include <hip/hip_runtime.h>

// Problem constants (from reference)
#define EMBED_DIM 200
#define NUM_WALKS 25
#define NUM_LAYERS 3
#define BATCH 8192

// One wave (64 lanes) per batch element. Row indices are WAVE-UNIFORM, so we
// read them via scalar loads (s_load) and issue embedding-row gathers as
// saddr-form global_load_dwordx4 (SGPR base + one shared lane-offset VGPR).
// This removes the shfl/bpermute dependency and per-lane 64-bit address math
// from the load chain, maximizing outstanding loads per wave.
__global__ __launch_bounds__(256) void gnp_score_kernel(
    const float* __restrict__ emb,      // [1e6, 200]
    const float* __restrict__ lw,       // [4] layer weights (pre-softmax)
    const int*   __restrict__ uidx,     // [B]
    const int*   __restrict__ iidx,     // [B]
    const int*   __restrict__ uwalks,   // [B, 25, 4]
    const int*   __restrict__ iwalks,   // [B, 25, 4]
    float*       __restrict__ out)      // [B]
{
    const int lane = threadIdx.x & 63;
    // Wave-uniform batch element, forced into an SGPR.
    const int b = __builtin_amdgcn_readfirstlane(blockIdx.x * 4 + (threadIdx.x >> 6));

    // softmax over 4 layer weights (uniform values; cheap)
    const float l0 = lw[0], l1 = lw[1], l2 = lw[2], l3 = lw[3];
    const float mx = fmaxf(fmaxf(l0, l1), fmaxf(l2, l3));
    const float e0 = expf(l0 - mx), e1 = expf(l1 - mx);
    const float e2 = expf(l2 - mx), e3 = expf(l3 - mx);
    const float inv = 1.0f / (e0 + e1 + e2 + e3);
    const float w0 = e0 * inv;                         // base-row weight
    const float c1 = e1 * inv * (1.0f / NUM_WALKS);    // layer-mean weights / 25
    const float c2 = e2 * inv * (1.0f / NUM_WALKS);
    const float c3 = e3 * inv * (1.0f / NUM_WALKS);

    // Lanes 50..63 alias lane 49's slice (same 16 B -> broadcast, no extra
    // HBM traffic); their contribution is zeroed at the reduction.
    const int dl = (lane < 50) ? lane : 49;
    const unsigned doff = (unsigned)dl * 4u;   // float offset within row

    const int* __restrict__ uw = uwalks + b * 100;  // uniform base
    const int* __restrict__ iw = iwalks + b * 100;

    float4 au, ai;
    {
        // Base rows (weight w0). uidx[b]/iidx[b] are uniform -> s_load.
        const unsigned su = (unsigned)uidx[b];
        const unsigned si = (unsigned)iidx[b];
        const float4 uv = *(const float4*)(emb + (size_t)su * 200u + doff);
        const float4 iv = *(const float4*)(emb + (size_t)si * 200u + doff);
        au.x = w0 * uv.x; au.y = w0 * uv.y; au.z = w0 * uv.z; au.w = w0 * uv.w;
        ai.x = w0 * iv.x; ai.y = w0 * iv.y; ai.z = w0 * iv.z; ai.w = w0 * iv.w;
    }

    // Walk rows: layers k=1..3 (walks[:, :, 1:]), weight c_k = softmax_k/25.
    // All indices are uniform scalar loads; row loads are independent
    // saddr-form dwordx4 -> deep VMEM pipelining.
    #pragma unroll
    for (int w = 0; w < NUM_WALKS; ++w) {
        #pragma unroll
        for (int k = 1; k <= NUM_LAYERS; ++k) {
            const float c = (k == 1) ? c1 : (k == 2) ? c2 : c3;
            const unsigned su = (unsigned)uw[w * 4 + k];
            const unsigned si = (unsigned)iw[w * 4 + k];
            const float4 uv = *(const float4*)(emb + (size_t)su * 200u + doff);
            const float4 iv = *(const float4*)(emb + (size_t)si * 200u + doff);
            au.x = fmaf(c, uv.x, au.x); au.y = fmaf(c, uv.y, au.y);
            au.z = fmaf(c, uv.z, au.z); au.w = fmaf(c, uv.w, au.w);
            ai.x = fmaf(c, iv.x, ai.x); ai.y = fmaf(c, iv.y, ai.y);
            ai.z = fmaf(c, iv.z, ai.z); ai.w = fmaf(c, iv.w, ai.w);
        }
    }

    float partial = au.x * ai.x + au.y * ai.y + au.z * ai.z + au.w * ai.w;
    if (lane >= 50) partial = 0.0f;   // drop the aliased lanes

    // Wave-wide sum; all 64 lanes execute.
    #pragma unroll
    for (int off = 32; off > 0; off >>= 1)
        partial += __shfl_xor(partial, off, 64);

    if (lane == 0) out[b] = partial;
}

extern "C" void kernel_launch(void* const* d_in, const int* in_sizes, int n_in,
                              void* d_out, int out_size, void* d_ws, size_t ws_size,
                              hipStream_t stream) {
    const float* emb    = (const float*)d_in[0];
    const float* lw     = (const float*)d_in[1];
    const int*   uidx   = (const int*)d_in[2];
    const int*   iidx   = (const int*)d_in[3];
    const int*   uwalks = (const int*)d_in[4];
    const int*   iwalks = (const int*)d_in[5];
    float*       out    = (float*)d_out;

    // 4 waves (elements) per 256-thread block
    const int blocks = BATCH / 4;  // 2048
    gnp_score_kernel<<<blocks, 256, 0, stream>>>(emb, lw, uidx, iidx,
                                                 uwalks, iwalks, out);
}